// Round 8
// baseline (256.682 us; speedup 1.0000x reference)
//
#include <hip/hip_runtime.h>

// Levenshtein edit distance, ref (512,B) x hyp (512,B), B=1024, unit costs.
// Anti-diagonal wavefront, one 64-lane wave per problem, 8 cells/lane packed
// 2-per-register in PARITY-STRIDED layout: reg p = cells {p, p+4} (lo,hi).
//
// r14: 4 waves/SIMD concentration — 64 blocks x 1024 threads (16 waves per
// block => one CU per block, 4 waves/SIMD). Model from r11+r13b counters:
// each VALU instr costs ~4 equiv-cyc (execute floor 112 cyc/step; busy
// 105-106 measured in BOTH geometries), and per-SIMD idle is SUB-LINEAR in
// wave count (58 cyc at 1 wave, 66 total at 2 waves). r13b's 2-waves/half-
// GPU lost net (1.17x per-SIMD for 2x fewer SIMDs); at 4 waves/SIMD the
// packing ratio projects to ~3.2-3.9x per-SIMD for 4x fewer CUs => ~56us.
// Execute floor bounds upside at 47.8us; per-wave-fixed idle bounds the
// downside at ~flat 72us.
// Micro-tweak: pkadd(nq,neg2) -> v_or_b32(neg2,nq): nq in {0,1} per half,
// OR 0xFFFE = {0xFFFE,0xFFFF} = nq-2 mod 2^16 — bit-identical, VOP2.
//
// Per-step VALU: 2 dpp + 2 alignbit + 4 xor + 4 or + 16 pk = 28.
//
// Biased relative domain (exact, r7-verified): w = v - d + 1024 in [0,1024].
//   AN = min(a1s, A1, a2s + nq - 2),  nq = (ref!=hyp) via min_u16(xor,1)
// i=0 boundary: constant 1024 via persistent vseam lane0. j=0 boundary:
// fake-init 0x3FFF (decays <=2/step -> >=14337 at end, never beats real).
// Token loads exist only for d<=517 (injections at d>=514 provably cannot
// reach the answer cell); second half of the kernel is load-free.

#define HLEN 512
#define BATCH 1024
#define FAKE2  0x3FFF3FFFu  // packed fake-infinity
#define SENT2  0x03FF03FFu  // packed token sentinel (real tokens < 1000)
#define BIASHI 0x04000000u  // 1024 in high half: persistent lane0 of vseam
#define ONE2   0x00010001u
#define NEG22  0xFFFEFFFEu  // -2 per 16-bit lane (OR-mask form)

// lane L gets src from lane L-1; lane 0 KEEPS OLD DEST (gfx9 DPP WAVE_SHR1,
// bound_ctrl=false, old operand tied to dest). HW-verified rounds 3-7.
__device__ __forceinline__ unsigned upd_dpp(unsigned old, unsigned src) {
  return (unsigned)__builtin_amdgcn_update_dpp((int)old, (int)src, 0x138, 0xF, 0xF, false);
}

// One diagonal step. A2/A1/AN: unsigned[4] parity-packed diagonals.
// TREG: token reg — bits[31:16] = injected token (global_load_short_d16_hi
// dest), consumed in place as the dpp tied-old. Hand-scheduled asm:
// dependent ops kept >=3 instructions apart.
#define STEP(A2, A1, AN, Q0, Q1, Q2, Q3, TREG)                          \
  do {                                                                  \
    unsigned t0, t1, t2, t3, m0, m1, m2, m3, a1s0, hn;                  \
    vseam = upd_dpp(vseam, A1[3]); /* lane0 stays BIASHI */             \
    TREG = upd_dpp(TREG, Q3);      /* lane0 keeps loaded tok<<16 */     \
    asm("v_xor_b32 %[t1], %[rt1], %[q0]\n\t"                            \
        "v_xor_b32 %[t2], %[rt2], %[q1]\n\t"                            \
        "v_xor_b32 %[t3], %[rt3], %[q2]\n\t"                            \
        "v_alignbit_b32 %[a1s0], %[a13], %[vs], 16\n\t"                 \
        "v_alignbit_b32 %[hn], %[q3], %[tq], 16\n\t"                    \
        : [t1]"=&v"(t1), [t2]"=&v"(t2), [t3]"=&v"(t3),                  \
          [a1s0]"=&v"(a1s0), [hn]"=&v"(hn)                              \
        : [rt1]"v"(rt[1]), [rt2]"v"(rt[2]), [rt3]"v"(rt[3]),            \
          [q0]"v"(Q0), [q1]"v"(Q1), [q2]"v"(Q2), [q3]"v"(Q3),           \
          [a13]"v"(A1[3]), [vs]"v"(vseam), [tq]"v"(TREG));              \
    asm("v_pk_min_u16 %[t1], %[t1], %[one]\n\t"                         \
        "v_pk_min_u16 %[t2], %[t2], %[one]\n\t"                         \
        "v_xor_b32    %[t0], %[rt0], %[hn]\n\t"                         \
        "v_pk_min_u16 %[t3], %[t3], %[one]\n\t"                         \
        "v_or_b32     %[t1], %[neg2], %[t1]\n\t"                        \
        "v_pk_min_u16 %[t0], %[t0], %[one]\n\t"                         \
        "v_or_b32     %[t2], %[neg2], %[t2]\n\t"                        \
        "v_or_b32     %[t3], %[neg2], %[t3]\n\t"                        \
        "v_pk_add_u16 %[t1], %[t1], %[a20]\n\t"                         \
        "v_or_b32     %[t0], %[neg2], %[t0]\n\t"                        \
        "v_pk_min_u16 %[m3], %[a12], %[a13]\n\t"                        \
        "v_pk_min_u16 %[m1], %[a10], %[a11]\n\t"                        \
        "v_pk_add_u16 %[t2], %[t2], %[a21]\n\t"                         \
        "v_pk_add_u16 %[t3], %[t3], %[a22]\n\t"                         \
        "v_pk_add_u16 %[t0], %[t0], %[s0c]\n\t"                         \
        "v_pk_min_u16 %[m2], %[a11], %[a12]\n\t"                        \
        "v_pk_min_u16 %[m0], %[a1s0], %[a10]\n\t"                       \
        "v_pk_min_u16 %[t3], %[m3], %[t3]\n\t"                          \
        "v_pk_min_u16 %[t1], %[m1], %[t1]\n\t"                          \
        "v_pk_min_u16 %[t2], %[m2], %[t2]\n\t"                          \
        "v_pk_min_u16 %[t0], %[m0], %[t0]\n\t"                          \
        : [t0]"=&v"(t0), [t1]"+v"(t1), [t2]"+v"(t2), [t3]"+v"(t3),      \
          [m0]"=&v"(m0), [m1]"=&v"(m1), [m2]"=&v"(m2), [m3]"=&v"(m3)    \
        : [hn]"v"(hn), [a1s0]"v"(a1s0),                                 \
          [a10]"v"(A1[0]), [a11]"v"(A1[1]), [a12]"v"(A1[2]),            \
          [a13]"v"(A1[3]),                                              \
          [a20]"v"(A2[0]), [a21]"v"(A2[1]), [a22]"v"(A2[2]),            \
          [rt0]"v"(rt[0]), [one]"v"(one2), [neg2]"v"(neg2),             \
          [s0c]"v"(s0c));                                               \
    AN[0] = t0; AN[1] = t1; AN[2] = t2; AN[3] = t3;                     \
    s0c = a1s0;                                                         \
    Q3 = hn;                                                            \
  } while (0)

// Broadcast token load: all lanes read the SAME 2 bytes into the HIGH half
// of DST (low half preserved/garbage — discarded by the alignbit). Address
// is wave-uniform: SGPR-pair base advanced on the SCALAR pipe (+4096 B/row).
#define TLOAD(DST) do {                                                \
    asm volatile("global_load_short_d16_hi %0, %1, %2"                 \
                 : "+v"(DST) : "v"(vz), "s"(hb2));                     \
    hb2 += 2048; /* +4096 bytes, uniform -> s_add/s_addc */            \
  } while (0)
// Frozen variant: load without advancing (compile-time clamp to token 511).
#define TLOADF(DST) do {                                               \
    asm volatile("global_load_short_d16_hi %0, %1, %2"                 \
                 : "+v"(DST) : "v"(vz), "s"(hb2));                     \
  } while (0)

// Counted waits tied to the consumed bank (rule #18 hoist fence).
#define TWAIT12(T)                                                     \
  asm volatile("s_waitcnt vmcnt(12)"                                   \
               : "+v"(T[0]), "+v"(T[1]), "+v"(T[2]), "+v"(T[3]),       \
                 "+v"(T[4]), "+v"(T[5]), "+v"(T[6]), "+v"(T[7]),       \
                 "+v"(T[8]), "+v"(T[9]), "+v"(T[10]), "+v"(T[11]));
#define TWAIT0(T)                                                      \
  asm volatile("s_waitcnt vmcnt(0)"                                    \
               : "+v"(T[0]), "+v"(T[1]), "+v"(T[2]), "+v"(T[3]),       \
                 "+v"(T[4]), "+v"(T[5]), "+v"(T[6]), "+v"(T[7]),       \
                 "+v"(T[8]), "+v"(T[9]), "+v"(T[10]), "+v"(T[11]));

#define STEPS12(T)                                                     \
    STEP(A, Bv, Cv, q0, q1, q2, q3, T[0]);                             \
    STEP(Bv, Cv, A, q3, q0, q1, q2, T[1]);                             \
    STEP(Cv, A, Bv, q2, q3, q0, q1, T[2]);                             \
    STEP(A, Bv, Cv, q1, q2, q3, q0, T[3]);                             \
    STEP(Bv, Cv, A, q0, q1, q2, q3, T[4]);                             \
    STEP(Cv, A, Bv, q3, q0, q1, q2, T[5]);                             \
    STEP(A, Bv, Cv, q2, q3, q0, q1, T[6]);                             \
    STEP(Bv, Cv, A, q1, q2, q3, q0, T[7]);                             \
    STEP(Cv, A, Bv, q0, q1, q2, q3, T[8]);                             \
    STEP(A, Bv, Cv, q3, q0, q1, q2, T[9]);                             \
    STEP(Bv, Cv, A, q2, q3, q0, q1, T[10]);                            \
    STEP(Cv, A, Bv, q1, q2, q3, q0, T[11]);

__global__ void __launch_bounds__(1024)
edit_distance_kernel(const int* __restrict__ ref,
                     const int* __restrict__ hyp,
                     float* __restrict__ out) {
  // 16 waves per block, one problem per wave; block owns one CU -> 4 waves
  // per SIMD (max TLP enforceable by block granularity).
  // readfirstlane forces the wave-id scalar so hb2 stays in SGPRs.
  const int wvid = __builtin_amdgcn_readfirstlane((int)(threadIdx.x >> 6));
  const int b = blockIdx.x * 16 + wvid;
  const int lane = threadIdx.x & 63;

  // Parity-packed static ref tokens: rt[p] = {cell lane*8+p, cell lane*8+p+4}.
  unsigned rt[4];
#pragma unroll
  for (int p = 0; p < 4; ++p) {
    unsigned lo = (unsigned)ref[(lane * 8 + p) * BATCH + b];
    unsigned hi = (unsigned)ref[(lane * 8 + p + 4) * BATCH + b];
    rt[p] = lo | (hi << 16);
  }

  // Uniform token pointer at this problem's column (token j's low 16 bits
  // live at byte j*4096 + b*4, little-endian). Advanced on the scalar pipe.
  const unsigned short* hb2 = (const unsigned short*)hyp + (unsigned)b * 2u;
  unsigned vz;
  asm("v_mov_b32 %0, 0" : "=v"(vz));  // constant-zero VGPR offset

  unsigned tA[12] = {0,0,0,0,0,0,0,0,0,0,0,0};
  unsigned tB[12] = {0,0,0,0,0,0,0,0,0,0,0,0};

  // Prologue prefetch: bank A = tokens 0-11 (iteration 0).
#pragma unroll
  for (int j = 0; j < 12; ++j) TLOAD(tA[j]);

  const unsigned one2 = ONE2;
  const unsigned neg2 = NEG22;

  // Rotating parity-packed diagonal buffers.
  unsigned A[4], Bv[4], Cv[4];
#pragma unroll
  for (int p = 0; p < 4; ++p) { A[p] = FAKE2; Bv[p] = FAKE2; }
  if (lane == 0) Bv[0] = 0x3FFF0400u;  // cell 0 (lo half) on diag 1: w=1024

  // Token queue (parity-packed), all sentinels.
  unsigned q0 = SENT2, q1 = SENT2, q2 = SENT2, q3 = SENT2;

  // Persistent DPP staging register: lane0 = 1024 bias, preserved forever
  // (bound_ctrl=false keeps old dest on lane0; lanes >=1 get overwritten).
  unsigned vseam = BIASHI;

  // Carried shifted-A2 seam: shifted diag-0 (all fake, lane0 lo = 1024).
  unsigned s0c;
  vseam = upd_dpp(vseam, A[3]);
  s0c = __builtin_amdgcn_alignbit(A[3], vseam, 16);

  // ---- Token phase: iterations 0..42 (d = 2..517), double-buffered. ----
#pragma clang loop unroll(disable)
  for (int p = 0; p < 20; ++p) {
    // Body A: prefetch bank B (it=2p+1), consume bank A (it=2p).
#pragma unroll
    for (int j = 0; j < 12; ++j) TLOAD(tB[j]);
    TWAIT12(tA);
    STEPS12(tA);
    // Body B: prefetch bank A (it=2p+2), consume bank B (it=2p+1).
#pragma unroll
    for (int j = 0; j < 12; ++j) TLOAD(tA[j]);
    TWAIT12(tB);
    STEPS12(tB);
  }
  // it=40 in bank A. Load it=41 (tokens 492-503), consume it=40.
#pragma unroll
  for (int j = 0; j < 12; ++j) TLOAD(tB[j]);
  TWAIT12(tA);
  STEPS12(tA);
  // Load it=42: tokens 504-510 advancing, then frozen at 511 (j=7..11;
  // j>=8 inject at d>=514 = provably irrelevant, j=7 needs real 511).
#pragma unroll
  for (int j = 0; j < 7; ++j) TLOAD(tA[j]);
#pragma unroll
  for (int j = 7; j < 12; ++j) TLOADF(tA[j]);
  TWAIT12(tB);
  STEPS12(tB);   // it=41
  TWAIT0(tA);
  STEPS12(tA);   // it=42 (d = 506..517)

  // ---- Load-free phase: iterations 43..84 (d = 518..1021). Token regs
  // hold shifted junk; tokens injected at d>=518 cannot influence the
  // answer (need d+511 <= 1024). Queue keeps shifting real old tokens. ----
#pragma clang loop unroll(disable)
  for (int i = 0; i < 42; ++i) {
    STEPS12(tA);
  }

  // Epilogue: d = 1022, 1023, 1024 (garbage-region injections).
  STEP(A, Bv, Cv, q0, q1, q2, q3, tA[0]);
  STEP(Bv, Cv, A, q3, q0, q1, q2, tA[1]);
  STEP(Cv, A, Bv, q2, q3, q0, q1, tA[2]);

  // Answer: diag 1024 in Bv; cell 511 = lane 63, pair 3, HIGH half.
  // At d = 1024 = BIAS, w = v exactly.
  if (lane == 63) out[b] = (float)(Bv[3] >> 16);
}

extern "C" void kernel_launch(void* const* d_in, const int* in_sizes, int n_in,
                              void* d_out, int out_size, void* d_ws, size_t ws_size,
                              hipStream_t stream) {
  const int* ref = (const int*)d_in[0];
  const int* hyp = (const int*)d_in[1];
  float* out = (float*)d_out;
  edit_distance_kernel<<<BATCH / 16, 1024, 0, stream>>>(ref, hyp, out);
}

// Round 9
// 118.648 us; speedup vs baseline: 2.1634x; 2.1634x over previous
//
#include <hip/hip_runtime.h>

// Levenshtein edit distance, ref (512,B) x hyp (512,B), B=1024, unit costs.
// Anti-diagonal wavefront, one 64-lane wave per problem, 8 cells/lane packed
// 2-per-register in PARITY-STRIDED layout: reg p = cells {p, p+4} (lo,hi).
//
// r15 = r11 geometry restored (proven best: 72.3us) + r14's v_or tweak
// (bit-exact, validated) + paired-offset token loads (SALU halved).
//
// Measured HW model (r11/r13b/r14 three-point fit):
//  - busy/step is wave-invariant: ~110 cyc for 28 instrs = ~4 cyc/instr
//    execution for this VOP3P/DPP mix (active-CU VALUBusy 90% at 4 w/SIMD);
//  - at 1 wave/SIMD wall = ~6.06 cyc/instr (issue cadence; scheduling-
//    invariant per r10-r12 asm experiments);
//  - concentration trades CUs for sub-linear per-SIMD gain: net loss
//    (r13b 124us, r14 208us) => full GPU at 1 wave/SIMD is optimal, and
//    1024 problems cap us at exactly 1 wave/SIMD.
// => structural floor ~= 28 instr x 6.06 cyc x 1023 steps ~= 72us.
//
// Per-step VALU: 2 dpp + 2 alignbit + 4 xor + 4 or + 16 pk = 28.
//
// Biased relative domain (exact, r7-verified): w = v - d + 1024 in [0,1024].
//   AN = min(a1s, A1, a2s + nq - 2),  nq = (ref!=hyp) via min_u16(xor,1)
// i=0 boundary: constant 1024 via persistent vseam lane0. j=0 boundary:
// fake-init 0x3FFF (decays <=2/step -> >=14337 at end, never beats real).
// nq-2 via v_or 0xFFFE (nq in {0,1} per half -> {0xFFFE,0xFFFF} = nq-2
// mod 2^16, exact since true result >= 0).
// Token loads exist only for d<=517 (injections at d>=514 provably cannot
// reach the answer cell); second half of the kernel is load-free.

#define HLEN 512
#define BATCH 1024
#define FAKE2  0x3FFF3FFFu  // packed fake-infinity
#define SENT2  0x03FF03FFu  // packed token sentinel (real tokens < 1000)
#define BIASHI 0x04000000u  // 1024 in high half: persistent lane0 of vseam
#define ONE2   0x00010001u
#define NEG22  0xFFFEFFFEu  // -2 per 16-bit lane (OR-mask form)

// lane L gets src from lane L-1; lane 0 KEEPS OLD DEST (gfx9 DPP WAVE_SHR1,
// bound_ctrl=false, old operand tied to dest). HW-verified rounds 3-7.
__device__ __forceinline__ unsigned upd_dpp(unsigned old, unsigned src) {
  return (unsigned)__builtin_amdgcn_update_dpp((int)old, (int)src, 0x138, 0xF, 0xF, false);
}

// One diagonal step. A2/A1/AN: unsigned[4] parity-packed diagonals.
// TREG: token reg — bits[31:16] = injected token (global_load_short_d16_hi
// dest), consumed in place as the dpp tied-old. Hand-scheduled asm:
// dependent ops kept >=3 instructions apart.
#define STEP(A2, A1, AN, Q0, Q1, Q2, Q3, TREG)                          \
  do {                                                                  \
    unsigned t0, t1, t2, t3, m0, m1, m2, m3, a1s0, hn;                  \
    vseam = upd_dpp(vseam, A1[3]); /* lane0 stays BIASHI */             \
    TREG = upd_dpp(TREG, Q3);      /* lane0 keeps loaded tok<<16 */     \
    asm("v_xor_b32 %[t1], %[rt1], %[q0]\n\t"                            \
        "v_xor_b32 %[t2], %[rt2], %[q1]\n\t"                            \
        "v_xor_b32 %[t3], %[rt3], %[q2]\n\t"                            \
        "v_alignbit_b32 %[a1s0], %[a13], %[vs], 16\n\t"                 \
        "v_alignbit_b32 %[hn], %[q3], %[tq], 16\n\t"                    \
        : [t1]"=&v"(t1), [t2]"=&v"(t2), [t3]"=&v"(t3),                  \
          [a1s0]"=&v"(a1s0), [hn]"=&v"(hn)                              \
        : [rt1]"v"(rt[1]), [rt2]"v"(rt[2]), [rt3]"v"(rt[3]),            \
          [q0]"v"(Q0), [q1]"v"(Q1), [q2]"v"(Q2), [q3]"v"(Q3),           \
          [a13]"v"(A1[3]), [vs]"v"(vseam), [tq]"v"(TREG));              \
    asm("v_pk_min_u16 %[t1], %[t1], %[one]\n\t"                         \
        "v_pk_min_u16 %[t2], %[t2], %[one]\n\t"                         \
        "v_xor_b32    %[t0], %[rt0], %[hn]\n\t"                         \
        "v_pk_min_u16 %[t3], %[t3], %[one]\n\t"                         \
        "v_or_b32     %[t1], %[neg2], %[t1]\n\t"                        \
        "v_pk_min_u16 %[t0], %[t0], %[one]\n\t"                         \
        "v_or_b32     %[t2], %[neg2], %[t2]\n\t"                        \
        "v_or_b32     %[t3], %[neg2], %[t3]\n\t"                        \
        "v_pk_add_u16 %[t1], %[t1], %[a20]\n\t"                         \
        "v_or_b32     %[t0], %[neg2], %[t0]\n\t"                        \
        "v_pk_min_u16 %[m3], %[a12], %[a13]\n\t"                        \
        "v_pk_min_u16 %[m1], %[a10], %[a11]\n\t"                        \
        "v_pk_add_u16 %[t2], %[t2], %[a21]\n\t"                         \
        "v_pk_add_u16 %[t3], %[t3], %[a22]\n\t"                         \
        "v_pk_add_u16 %[t0], %[t0], %[s0c]\n\t"                         \
        "v_pk_min_u16 %[m2], %[a11], %[a12]\n\t"                        \
        "v_pk_min_u16 %[m0], %[a1s0], %[a10]\n\t"                       \
        "v_pk_min_u16 %[t3], %[m3], %[t3]\n\t"                          \
        "v_pk_min_u16 %[t1], %[m1], %[t1]\n\t"                          \
        "v_pk_min_u16 %[t2], %[m2], %[t2]\n\t"                          \
        "v_pk_min_u16 %[t0], %[m0], %[t0]\n\t"                          \
        : [t0]"=&v"(t0), [t1]"+v"(t1), [t2]"+v"(t2), [t3]"+v"(t3),      \
          [m0]"=&v"(m0), [m1]"=&v"(m1), [m2]"=&v"(m2), [m3]"=&v"(m3)    \
        : [hn]"v"(hn), [a1s0]"v"(a1s0),                                 \
          [a10]"v"(A1[0]), [a11]"v"(A1[1]), [a12]"v"(A1[2]),            \
          [a13]"v"(A1[3]),                                              \
          [a20]"v"(A2[0]), [a21]"v"(A2[1]), [a22]"v"(A2[2]),            \
          [rt0]"v"(rt[0]), [one]"v"(one2), [neg2]"v"(neg2),             \
          [s0c]"v"(s0c));                                               \
    AN[0] = t0; AN[1] = t1; AN[2] = t2; AN[3] = t3;                     \
    s0c = a1s0;                                                         \
    Q3 = hn;                                                            \
  } while (0)

// Paired broadcast token loads: base sits at (token j byte) + 4095 so two
// consecutive tokens (stride 4096 > 4095-imm) fit the 13-bit SIGNED offset
// as -4095 / +1. Base advances 8192 per pair: 1 SALU add-pair per 2 loads
// (halved vs r11). High half of DST gets the token (low half garbage,
// discarded by the alignbit). Loads are in-order for vmcnt.
#define TLOAD2(D0, D1) do {                                            \
    asm volatile("global_load_short_d16_hi %0, %1, %2 offset:-4095"    \
                 : "+v"(D0) : "v"(vz), "s"(hb));                       \
    asm volatile("global_load_short_d16_hi %0, %1, %2 offset:1"        \
                 : "+v"(D1) : "v"(vz), "s"(hb));                       \
    hb += 8192;                                                        \
  } while (0)
// Non-advancing variants for the ragged final block.
#define TLOAD2F(D0, D1) do {                                           \
    asm volatile("global_load_short_d16_hi %0, %1, %2 offset:-4095"    \
                 : "+v"(D0) : "v"(vz), "s"(hb));                       \
    asm volatile("global_load_short_d16_hi %0, %1, %2 offset:1"        \
                 : "+v"(D1) : "v"(vz), "s"(hb));                       \
  } while (0)
#define TLOADHI(D) do {                                                \
    asm volatile("global_load_short_d16_hi %0, %1, %2 offset:1"        \
                 : "+v"(D) : "v"(vz), "s"(hb));                        \
  } while (0)

// Counted waits tied to the consumed bank (rule #18 hoist fence).
#define TWAIT12(T)                                                     \
  asm volatile("s_waitcnt vmcnt(12)"                                   \
               : "+v"(T[0]), "+v"(T[1]), "+v"(T[2]), "+v"(T[3]),       \
                 "+v"(T[4]), "+v"(T[5]), "+v"(T[6]), "+v"(T[7]),       \
                 "+v"(T[8]), "+v"(T[9]), "+v"(T[10]), "+v"(T[11]));
#define TWAIT0(T)                                                      \
  asm volatile("s_waitcnt vmcnt(0)"                                    \
               : "+v"(T[0]), "+v"(T[1]), "+v"(T[2]), "+v"(T[3]),       \
                 "+v"(T[4]), "+v"(T[5]), "+v"(T[6]), "+v"(T[7]),       \
                 "+v"(T[8]), "+v"(T[9]), "+v"(T[10]), "+v"(T[11]));

#define TLOAD12(T)                                                     \
    TLOAD2(T[0], T[1]); TLOAD2(T[2], T[3]); TLOAD2(T[4], T[5]);        \
    TLOAD2(T[6], T[7]); TLOAD2(T[8], T[9]); TLOAD2(T[10], T[11]);

#define STEPS12(T)                                                     \
    STEP(A, Bv, Cv, q0, q1, q2, q3, T[0]);                             \
    STEP(Bv, Cv, A, q3, q0, q1, q2, T[1]);                             \
    STEP(Cv, A, Bv, q2, q3, q0, q1, T[2]);                             \
    STEP(A, Bv, Cv, q1, q2, q3, q0, T[3]);                             \
    STEP(Bv, Cv, A, q0, q1, q2, q3, T[4]);                             \
    STEP(Cv, A, Bv, q3, q0, q1, q2, T[5]);                             \
    STEP(A, Bv, Cv, q2, q3, q0, q1, T[6]);                             \
    STEP(Bv, Cv, A, q1, q2, q3, q0, T[7]);                             \
    STEP(Cv, A, Bv, q0, q1, q2, q3, T[8]);                             \
    STEP(A, Bv, Cv, q3, q0, q1, q2, T[9]);                             \
    STEP(Bv, Cv, A, q2, q3, q0, q1, T[10]);                            \
    STEP(Cv, A, Bv, q1, q2, q3, q0, T[11]);

__global__ void __launch_bounds__(64)
edit_distance_kernel(const int* __restrict__ ref,
                     const int* __restrict__ hyp,
                     float* __restrict__ out) {
  const int b = blockIdx.x;        // one wave (block of 64) per batch element
  const int lane = threadIdx.x;    // 0..63

  // Parity-packed static ref tokens: rt[p] = {cell lane*8+p, cell lane*8+p+4}.
  unsigned rt[4];
#pragma unroll
  for (int p = 0; p < 4; ++p) {
    unsigned lo = (unsigned)ref[(lane * 8 + p) * BATCH + b];
    unsigned hi = (unsigned)ref[(lane * 8 + p + 4) * BATCH + b];
    rt[p] = lo | (hi << 16);
  }

  // Uniform token base at this problem's column, biased +4095 for the
  // paired-offset scheme (token j's low 16 bits live at byte j*4096 + b*4).
  const char* hb = (const char*)hyp + (unsigned)b * 4u + 4095u;
  unsigned vz;
  asm("v_mov_b32 %0, 0" : "=v"(vz));  // constant-zero VGPR offset

  unsigned tA[12] = {0,0,0,0,0,0,0,0,0,0,0,0};
  unsigned tB[12] = {0,0,0,0,0,0,0,0,0,0,0,0};

  // Prologue prefetch: bank A = tokens 0-11 (iteration 0).
  TLOAD12(tA);

  const unsigned one2 = ONE2;
  const unsigned neg2 = NEG22;

  // Rotating parity-packed diagonal buffers.
  unsigned A[4], Bv[4], Cv[4];
#pragma unroll
  for (int p = 0; p < 4; ++p) { A[p] = FAKE2; Bv[p] = FAKE2; }
  if (lane == 0) Bv[0] = 0x3FFF0400u;  // cell 0 (lo half) on diag 1: w=1024

  // Token queue (parity-packed), all sentinels.
  unsigned q0 = SENT2, q1 = SENT2, q2 = SENT2, q3 = SENT2;

  // Persistent DPP staging register: lane0 = 1024 bias, preserved forever
  // (bound_ctrl=false keeps old dest on lane0; lanes >=1 get overwritten).
  unsigned vseam = BIASHI;

  // Carried shifted-A2 seam: shifted diag-0 (all fake, lane0 lo = 1024).
  unsigned s0c;
  vseam = upd_dpp(vseam, A[3]);
  s0c = __builtin_amdgcn_alignbit(A[3], vseam, 16);

  // ---- Token phase: iterations 0..42 (d = 2..517), double-buffered. ----
#pragma clang loop unroll(disable)
  for (int p = 0; p < 20; ++p) {
    // Body A: prefetch bank B (it=2p+1), consume bank A (it=2p).
    TLOAD12(tB);
    TWAIT12(tA);
    STEPS12(tA);
    // Body B: prefetch bank A (it=2p+2), consume bank B (it=2p+1).
    TLOAD12(tA);
    TWAIT12(tB);
    STEPS12(tB);
  }
  // it=40 in bank A. Load it=41 (tokens 492-503), consume it=40.
  TLOAD12(tB);
  TWAIT12(tA);
  STEPS12(tA);
  // Load it=42: tokens 504-510, then frozen at 511 (j=7..11; j>=8 inject
  // at d>=514 = provably irrelevant, j=7 needs real 511). Final pair
  // (510,511) and the 4 frozen 511s do not advance the base (in-bounds).
  TLOAD2(tA[0], tA[1]);   // 504,505
  TLOAD2(tA[2], tA[3]);   // 506,507
  TLOAD2(tA[4], tA[5]);   // 508,509
  TLOAD2F(tA[6], tA[7]);  // 510,511 (no advance)
  TLOADHI(tA[8]);         // 511
  TLOADHI(tA[9]);         // 511
  TLOADHI(tA[10]);        // 511
  TLOADHI(tA[11]);        // 511
  TWAIT12(tB);
  STEPS12(tB);   // it=41
  TWAIT0(tA);
  STEPS12(tA);   // it=42 (d = 506..517)

  // ---- Load-free phase: iterations 43..84 (d = 518..1021). Token regs
  // hold shifted junk; tokens injected at d>=518 cannot influence the
  // answer (need d+511 <= 1024). Queue keeps shifting real old tokens. ----
#pragma clang loop unroll(disable)
  for (int i = 0; i < 42; ++i) {
    STEPS12(tA);
  }

  // Epilogue: d = 1022, 1023, 1024 (garbage-region injections).
  STEP(A, Bv, Cv, q0, q1, q2, q3, tA[0]);
  STEP(Bv, Cv, A, q3, q0, q1, q2, tA[1]);
  STEP(Cv, A, Bv, q2, q3, q0, q1, tA[2]);

  // Answer: diag 1024 in Bv; cell 511 = lane 63, pair 3, HIGH half.
  // At d = 1024 = BIAS, w = v exactly.
  if (lane == 63) out[b] = (float)(Bv[3] >> 16);
}

extern "C" void kernel_launch(void* const* d_in, const int* in_sizes, int n_in,
                              void* d_out, int out_size, void* d_ws, size_t ws_size,
                              hipStream_t stream) {
  const int* ref = (const int*)d_in[0];
  const int* hyp = (const int*)d_in[1];
  float* out = (float*)d_out;
  edit_distance_kernel<<<BATCH, 64, 0, stream>>>(ref, hyp, out);
}

// Round 10
// 111.632 us; speedup vs baseline: 2.2994x; 1.0628x over previous
//
#include <hip/hip_runtime.h>

// Levenshtein edit distance, ref (512,B) x hyp (512,B), B=1024, unit costs.
// Anti-diagonal wavefront, one 64-lane wave per problem, 8 cells/lane packed
// 2-per-register in PARITY-STRIDED layout: reg p = cells {p, p+4} (lo,hi).
//
// r16 = r15 + SATURATING-ADD FOLD: nq-2 was or(min_u16(xor,1),0xFFFE)
// (2 ops); unsigned-saturating v_pk_add_u16 ... clamp computes
// sat(t+0xFFFE) = {t==0 -> 0xFFFE, t>=1 -> 0xFFFF} in ONE op. The
// following +a2s add stays modular (no clamp) — bit-exact with r15.
// Per-step VALU: 2 dpp + 2 alignbit + 4 xor + 4 addclamp + 4 add + 8 min
// = 24 (was 28).
//
// Measured HW model (r11/r13b/r14/r15 fits):
//  - time/step = instr_count x ~2.47 ns at 1 wave/SIMD (cadence+exec;
//    scheduling-invariant per r10-r12; geometry-optimal per r13b/r14);
//  - 28 instr -> 69.1 ns/step (r15: 70.7us). 24 instr -> ~59-61 ns
//    predicted -> ~61us kernel. Flat result = fixed per-step latency
//    floor -> roofline.
//
// Biased relative domain (exact, r7-verified): w = v - d + 1024 in [0,1024].
//   AN = min(a1s, A1, a2s + nq - 2),  nq = (ref!=hyp)
// i=0 boundary: constant 1024 via persistent vseam lane0. j=0 boundary:
// fake-init 0x3FFF (decays <=2/step -> >=14337 at end, never beats real).
// Token loads exist only for d<=517 (injections at d>=514 provably cannot
// reach the answer cell); second half of the kernel is load-free.

#define HLEN 512
#define BATCH 1024
#define FAKE2  0x3FFF3FFFu  // packed fake-infinity
#define SENT2  0x03FF03FFu  // packed token sentinel (real tokens < 1000)
#define BIASHI 0x04000000u  // 1024 in high half: persistent lane0 of vseam
#define NEG22  0xFFFEFFFEu  // -2 per 16-bit lane (saturating addend)

// lane L gets src from lane L-1; lane 0 KEEPS OLD DEST (gfx9 DPP WAVE_SHR1,
// bound_ctrl=false, old operand tied to dest). HW-verified rounds 3-7.
__device__ __forceinline__ unsigned upd_dpp(unsigned old, unsigned src) {
  return (unsigned)__builtin_amdgcn_update_dpp((int)old, (int)src, 0x138, 0xF, 0xF, false);
}

// One diagonal step. A2/A1/AN: unsigned[4] parity-packed diagonals.
// TREG: token reg — bits[31:16] = injected token (global_load_short_d16_hi
// dest), consumed in place as the dpp tied-old. Hand-scheduled asm:
// dependent ops kept >=4 instructions apart.
// Per-pair chain: t = xor(rt,q); t = sat(t + 0xFFFE)  [clamp: {FFFE,FFFF}];
// t = t + a2s (modular); AN = min(min(a1s,a1), t).
#define STEP(A2, A1, AN, Q0, Q1, Q2, Q3, TREG)                          \
  do {                                                                  \
    unsigned t0, t1, t2, t3, m0, m1, m2, m3, a1s0, hn;                  \
    vseam = upd_dpp(vseam, A1[3]); /* lane0 stays BIASHI */             \
    TREG = upd_dpp(TREG, Q3);      /* lane0 keeps loaded tok<<16 */     \
    asm("v_xor_b32 %[t1], %[rt1], %[q0]\n\t"                            \
        "v_xor_b32 %[t2], %[rt2], %[q1]\n\t"                            \
        "v_xor_b32 %[t3], %[rt3], %[q2]\n\t"                            \
        "v_alignbit_b32 %[a1s0], %[a13], %[vs], 16\n\t"                 \
        "v_alignbit_b32 %[hn], %[q3], %[tq], 16\n\t"                    \
        : [t1]"=&v"(t1), [t2]"=&v"(t2), [t3]"=&v"(t3),                  \
          [a1s0]"=&v"(a1s0), [hn]"=&v"(hn)                              \
        : [rt1]"v"(rt[1]), [rt2]"v"(rt[2]), [rt3]"v"(rt[3]),            \
          [q0]"v"(Q0), [q1]"v"(Q1), [q2]"v"(Q2), [q3]"v"(Q3),           \
          [a13]"v"(A1[3]), [vs]"v"(vseam), [tq]"v"(TREG));              \
    asm("v_pk_add_u16 %[t1], %[t1], %[neg2] clamp\n\t"                  \
        "v_pk_add_u16 %[t2], %[t2], %[neg2] clamp\n\t"                  \
        "v_pk_add_u16 %[t3], %[t3], %[neg2] clamp\n\t"                  \
        "v_xor_b32    %[t0], %[rt0], %[hn]\n\t"                         \
        "v_pk_min_u16 %[m1], %[a10], %[a11]\n\t"                        \
        "v_pk_min_u16 %[m2], %[a11], %[a12]\n\t"                        \
        "v_pk_min_u16 %[m3], %[a12], %[a13]\n\t"                        \
        "v_pk_add_u16 %[t1], %[t1], %[a20]\n\t"                         \
        "v_pk_add_u16 %[t0], %[t0], %[neg2] clamp\n\t"                  \
        "v_pk_add_u16 %[t2], %[t2], %[a21]\n\t"                         \
        "v_pk_add_u16 %[t3], %[t3], %[a22]\n\t"                         \
        "v_pk_min_u16 %[m0], %[a1s0], %[a10]\n\t"                       \
        "v_pk_add_u16 %[t0], %[t0], %[s0c]\n\t"                         \
        "v_pk_min_u16 %[t1], %[m1], %[t1]\n\t"                          \
        "v_pk_min_u16 %[t2], %[m2], %[t2]\n\t"                          \
        "v_pk_min_u16 %[t3], %[m3], %[t3]\n\t"                          \
        "v_pk_min_u16 %[t0], %[m0], %[t0]\n\t"                          \
        : [t0]"=&v"(t0), [t1]"+v"(t1), [t2]"+v"(t2), [t3]"+v"(t3),      \
          [m0]"=&v"(m0), [m1]"=&v"(m1), [m2]"=&v"(m2), [m3]"=&v"(m3)    \
        : [hn]"v"(hn), [a1s0]"v"(a1s0),                                 \
          [a10]"v"(A1[0]), [a11]"v"(A1[1]), [a12]"v"(A1[2]),            \
          [a13]"v"(A1[3]),                                              \
          [a20]"v"(A2[0]), [a21]"v"(A2[1]), [a22]"v"(A2[2]),            \
          [rt0]"v"(rt[0]), [neg2]"v"(neg2),                             \
          [s0c]"v"(s0c));                                               \
    AN[0] = t0; AN[1] = t1; AN[2] = t2; AN[3] = t3;                     \
    s0c = a1s0;                                                         \
    Q3 = hn;                                                            \
  } while (0)

// Paired broadcast token loads: base sits at (token j byte) + 4095 so two
// consecutive tokens (stride 4096) fit the 13-bit SIGNED offset as
// -4095 / +1. Base advances 8192 per pair: 1 SALU add-pair per 2 loads.
// High half of DST gets the token (low half garbage, discarded by the
// alignbit). Loads are in-order for vmcnt.
#define TLOAD2(D0, D1) do {                                            \
    asm volatile("global_load_short_d16_hi %0, %1, %2 offset:-4095"    \
                 : "+v"(D0) : "v"(vz), "s"(hb));                       \
    asm volatile("global_load_short_d16_hi %0, %1, %2 offset:1"        \
                 : "+v"(D1) : "v"(vz), "s"(hb));                       \
    hb += 8192;                                                        \
  } while (0)
// Non-advancing variants for the ragged final block.
#define TLOAD2F(D0, D1) do {                                           \
    asm volatile("global_load_short_d16_hi %0, %1, %2 offset:-4095"    \
                 : "+v"(D0) : "v"(vz), "s"(hb));                       \
    asm volatile("global_load_short_d16_hi %0, %1, %2 offset:1"        \
                 : "+v"(D1) : "v"(vz), "s"(hb));                       \
  } while (0)
#define TLOADHI(D) do {                                                \
    asm volatile("global_load_short_d16_hi %0, %1, %2 offset:1"        \
                 : "+v"(D) : "v"(vz), "s"(hb));                        \
  } while (0)

// Counted waits tied to the consumed bank (rule #18 hoist fence).
#define TWAIT12(T)                                                     \
  asm volatile("s_waitcnt vmcnt(12)"                                   \
               : "+v"(T[0]), "+v"(T[1]), "+v"(T[2]), "+v"(T[3]),       \
                 "+v"(T[4]), "+v"(T[5]), "+v"(T[6]), "+v"(T[7]),       \
                 "+v"(T[8]), "+v"(T[9]), "+v"(T[10]), "+v"(T[11]));
#define TWAIT0(T)                                                      \
  asm volatile("s_waitcnt vmcnt(0)"                                    \
               : "+v"(T[0]), "+v"(T[1]), "+v"(T[2]), "+v"(T[3]),       \
                 "+v"(T[4]), "+v"(T[5]), "+v"(T[6]), "+v"(T[7]),       \
                 "+v"(T[8]), "+v"(T[9]), "+v"(T[10]), "+v"(T[11]));

#define TLOAD12(T)                                                     \
    TLOAD2(T[0], T[1]); TLOAD2(T[2], T[3]); TLOAD2(T[4], T[5]);        \
    TLOAD2(T[6], T[7]); TLOAD2(T[8], T[9]); TLOAD2(T[10], T[11]);

#define STEPS12(T)                                                     \
    STEP(A, Bv, Cv, q0, q1, q2, q3, T[0]);                             \
    STEP(Bv, Cv, A, q3, q0, q1, q2, T[1]);                             \
    STEP(Cv, A, Bv, q2, q3, q0, q1, T[2]);                             \
    STEP(A, Bv, Cv, q1, q2, q3, q0, T[3]);                             \
    STEP(Bv, Cv, A, q0, q1, q2, q3, T[4]);                             \
    STEP(Cv, A, Bv, q3, q0, q1, q2, T[5]);                             \
    STEP(A, Bv, Cv, q2, q3, q0, q1, T[6]);                             \
    STEP(Bv, Cv, A, q1, q2, q3, q0, T[7]);                             \
    STEP(Cv, A, Bv, q0, q1, q2, q3, T[8]);                             \
    STEP(A, Bv, Cv, q3, q0, q1, q2, T[9]);                             \
    STEP(Bv, Cv, A, q2, q3, q0, q1, T[10]);                            \
    STEP(Cv, A, Bv, q1, q2, q3, q0, T[11]);

__global__ void __launch_bounds__(64)
edit_distance_kernel(const int* __restrict__ ref,
                     const int* __restrict__ hyp,
                     float* __restrict__ out) {
  const int b = blockIdx.x;        // one wave (block of 64) per batch element
  const int lane = threadIdx.x;    // 0..63

  // Parity-packed static ref tokens: rt[p] = {cell lane*8+p, cell lane*8+p+4}.
  unsigned rt[4];
#pragma unroll
  for (int p = 0; p < 4; ++p) {
    unsigned lo = (unsigned)ref[(lane * 8 + p) * BATCH + b];
    unsigned hi = (unsigned)ref[(lane * 8 + p + 4) * BATCH + b];
    rt[p] = lo | (hi << 16);
  }

  // Uniform token base at this problem's column, biased +4095 for the
  // paired-offset scheme (token j's low 16 bits live at byte j*4096 + b*4).
  const char* hb = (const char*)hyp + (unsigned)b * 4u + 4095u;
  unsigned vz;
  asm("v_mov_b32 %0, 0" : "=v"(vz));  // constant-zero VGPR offset

  unsigned tA[12] = {0,0,0,0,0,0,0,0,0,0,0,0};
  unsigned tB[12] = {0,0,0,0,0,0,0,0,0,0,0,0};

  // Prologue prefetch: bank A = tokens 0-11 (iteration 0).
  TLOAD12(tA);

  const unsigned neg2 = NEG22;

  // Rotating parity-packed diagonal buffers.
  unsigned A[4], Bv[4], Cv[4];
#pragma unroll
  for (int p = 0; p < 4; ++p) { A[p] = FAKE2; Bv[p] = FAKE2; }
  if (lane == 0) Bv[0] = 0x3FFF0400u;  // cell 0 (lo half) on diag 1: w=1024

  // Token queue (parity-packed), all sentinels.
  unsigned q0 = SENT2, q1 = SENT2, q2 = SENT2, q3 = SENT2;

  // Persistent DPP staging register: lane0 = 1024 bias, preserved forever
  // (bound_ctrl=false keeps old dest on lane0; lanes >=1 get overwritten).
  unsigned vseam = BIASHI;

  // Carried shifted-A2 seam: shifted diag-0 (all fake, lane0 lo = 1024).
  unsigned s0c;
  vseam = upd_dpp(vseam, A[3]);
  s0c = __builtin_amdgcn_alignbit(A[3], vseam, 16);

  // ---- Token phase: iterations 0..42 (d = 2..517), double-buffered. ----
#pragma clang loop unroll(disable)
  for (int p = 0; p < 20; ++p) {
    // Body A: prefetch bank B (it=2p+1), consume bank A (it=2p).
    TLOAD12(tB);
    TWAIT12(tA);
    STEPS12(tA);
    // Body B: prefetch bank A (it=2p+2), consume bank B (it=2p+1).
    TLOAD12(tA);
    TWAIT12(tB);
    STEPS12(tB);
  }
  // it=40 in bank A. Load it=41 (tokens 492-503), consume it=40.
  TLOAD12(tB);
  TWAIT12(tA);
  STEPS12(tA);
  // Load it=42: tokens 504-510, then frozen at 511 (j=7..11; j>=8 inject
  // at d>=514 = provably irrelevant, j=7 needs real 511). Final pair
  // (510,511) and the 4 frozen 511s do not advance the base (in-bounds).
  TLOAD2(tA[0], tA[1]);   // 504,505
  TLOAD2(tA[2], tA[3]);   // 506,507
  TLOAD2(tA[4], tA[5]);   // 508,509
  TLOAD2F(tA[6], tA[7]);  // 510,511 (no advance)
  TLOADHI(tA[8]);         // 511
  TLOADHI(tA[9]);         // 511
  TLOADHI(tA[10]);        // 511
  TLOADHI(tA[11]);        // 511
  TWAIT12(tB);
  STEPS12(tB);   // it=41
  TWAIT0(tA);
  STEPS12(tA);   // it=42 (d = 506..517)

  // ---- Load-free phase: iterations 43..84 (d = 518..1021). Token regs
  // hold shifted junk; tokens injected at d>=518 cannot influence the
  // answer (need d+511 <= 1024). Queue keeps shifting real old tokens. ----
#pragma clang loop unroll(disable)
  for (int i = 0; i < 42; ++i) {
    STEPS12(tA);
  }

  // Epilogue: d = 1022, 1023, 1024 (garbage-region injections).
  STEP(A, Bv, Cv, q0, q1, q2, q3, tA[0]);
  STEP(Bv, Cv, A, q3, q0, q1, q2, tA[1]);
  STEP(Cv, A, Bv, q2, q3, q0, q1, tA[2]);

  // Answer: diag 1024 in Bv; cell 511 = lane 63, pair 3, HIGH half.
  // At d = 1024 = BIAS, w = v exactly.
  if (lane == 63) out[b] = (float)(Bv[3] >> 16);
}

extern "C" void kernel_launch(void* const* d_in, const int* in_sizes, int n_in,
                              void* d_out, int out_size, void* d_ws, size_t ws_size,
                              hipStream_t stream) {
  const int* ref = (const int*)d_in[0];
  const int* hyp = (const int*)d_in[1];
  float* out = (float*)d_out;
  edit_distance_kernel<<<BATCH, 64, 0, stream>>>(ref, hyp, out);
}